// Round 7
// baseline (37.916 us; speedup 1.0000x reference)
//
#include <hip/hip_runtime.h>

// PositionLossVal: offset [4,18,512,512] f32, optical_flow [4,8,512,512] f32 -> scalar f32.
// Per pixel: x=off[i], y=off[i+9] (i<9); u=flow[j], v=flow[j+1] (j<4).
// md = inside ? perp : min(d1,d2); min over j, mean over i, sum over b,h,w, /(h*w).
// min over j in squared domain -> 1 sqrt per (pixel,i).
// inside: x0*(x0-u)<=0, x0 = u*(x^2+v*y)/uu  <=>  w*(w-uu)<=0 with w = x^2+v*y.
//
// Ledger: R5 fused atomic tail = +60us (same-address device atomics serialize at the
// cross-XCD coherence point). R4 PPT=4 under a 128-VGPR cap = 1.1KB/thread spill.
// R2/R3/R6 (PPT=1/2 variants) all plateau at ~27us: latency-bound, VALUBusy ~34%,
// 64 VGPR can't hold enough loads in flight. This round: PPT=4 + float4 loads,
// NO wave-count cap -> lean body should land ~96-128 VGPR, 4 waves/SIMD, 4x the
// bytes-in-flight per wave, half the VMEM requests.

#define HW_BITS 18
#define HW_ (1 << HW_BITS)          // 512*512
#define NOFF 9
#define NFLOW 4
#define NPIX (4 * HW_)              // 1,048,576 pixels
#define PPT 4                       // pixels per thread (float4 loads)
#define BLK 256
#define GRID1 (NPIX / PPT / BLK)    // 1024 blocks
#define RBLK 1024

__global__ __launch_bounds__(BLK)   // block-size hint only; VGPR uncapped (R4 lesson)
void pos_loss_main(const float* __restrict__ off, const float* __restrict__ flow,
                   float* __restrict__ partial)
{
    const int t  = blockIdx.x * BLK + threadIdx.x;
    const int g  = t * PPT;                          // 4 consecutive pixels, same image
    const int b  = g >> HW_BITS;
    const int hw = g & (HW_ - 1);
    const float* offb = off  + ((size_t)b * (2 * NOFF)) * HW_ + hw;
    const float* flb  = flow + ((size_t)b * 8) * HW_ + hw;

    // Flow channels 0..4 as float4 (1KB per wave-instruction), live across the i-loop.
    float4 f4[NFLOW + 1];
#pragma unroll
    for (int j = 0; j <= NFLOW; ++j)
        f4[j] = *reinterpret_cast<const float4*>(flb + (size_t)j * HW_);

    // Per-(px,j) invariants: uu = u^2+v^2, r = 1/uu.  (32 regs, the only hoisted state)
    float uu_[PPT][NFLOW], r_[PPT][NFLOW];
#pragma unroll
    for (int j = 0; j < NFLOW; ++j) {
        const float up[PPT] = {f4[j].x, f4[j].y, f4[j].z, f4[j].w};
        const float vp[PPT] = {f4[j + 1].x, f4[j + 1].y, f4[j + 1].z, f4[j + 1].w};
#pragma unroll
        for (int p = 0; p < PPT; ++p) {
            const float uu = fmaf(up[p], up[p], vp[p] * vp[p]);
            uu_[p][j] = uu;
            r_[p][j]  = __builtin_amdgcn_rcpf(uu);
        }
    }

    float acc = 0.f;
#pragma unroll
    for (int i = 0; i < NOFF; ++i) {
        // Per-i float4 pair; uncapped VGPR lets the scheduler run several i-iterations
        // of loads ahead without spilling.
        const float4 x4 = *reinterpret_cast<const float4*>(offb + (size_t)i * HW_);
        const float4 y4 = *reinterpret_cast<const float4*>(offb + (size_t)(i + NOFF) * HW_);
        const float xp[PPT] = {x4.x, x4.y, x4.z, x4.w};
        const float yp[PPT] = {y4.x, y4.y, y4.z, y4.w};
#pragma unroll
        for (int p = 0; p < PPT; ++p) {
            const float x  = xp[p], y = yp[p];
            const float x2 = x * x;
            const float d1sq = fmaf(y, y, x2);
            float m2 = 1e30f;
#pragma unroll
            for (int j = 0; j < NFLOW; ++j) {
                const float u = (p == 0) ? f4[j].x : (p == 1) ? f4[j].y : (p == 2) ? f4[j].z : f4[j].w;
                const float v = (p == 0) ? f4[j + 1].x : (p == 1) ? f4[j + 1].y : (p == 2) ? f4[j + 1].z : f4[j + 1].w;
                const float w   = fmaf(v, y, x2);                 // x^2 + v*y
                const float ins = w * (w - uu_[p][j]);            // sign == x0*(x0-u)
                const float tt  = fmaf(v, x, -(u * y));           // v*x - u*y
                const float p2  = (tt * tt) * r_[p][j];
                const float dx = x - u, dy = y - v;
                const float d2sq = fmaf(dy, dy, dx * dx);
                const float e2  = fminf(d1sq, d2sq);
                const float md2 = (ins <= 0.f) ? p2 : e2;
                m2 = fminf(m2, md2);
            }
            acc += __builtin_amdgcn_sqrtf(m2);
        }
    }

    // Block reduction: wave shuffle -> LDS -> one partial per block (1024 partials).
#pragma unroll
    for (int o = 32; o > 0; o >>= 1) acc += __shfl_down(acc, o, 64);
    __shared__ float sm[BLK / 64];
    const int lane = threadIdx.x & 63, wid = threadIdx.x >> 6;
    if (lane == 0) sm[wid] = acc;
    __syncthreads();
    if (threadIdx.x == 0)
        partial[blockIdx.x] = sm[0] + sm[1] + sm[2] + sm[3];
}

__global__ __launch_bounds__(RBLK)
void pos_loss_reduce(const float* __restrict__ partial, float* __restrict__ out)
{
    float s = partial[threadIdx.x];                 // GRID1 == RBLK == 1024
#pragma unroll
    for (int o = 32; o > 0; o >>= 1) s += __shfl_down(s, o, 64);
    __shared__ float sm[RBLK / 64];                 // 16 wave sums
    const int lane = threadIdx.x & 63, wid = threadIdx.x >> 6;
    if (lane == 0) sm[wid] = s;
    __syncthreads();
    if (wid == 0) {
        float v = (lane < RBLK / 64) ? sm[lane] : 0.f;
#pragma unroll
        for (int o = 8; o > 0; o >>= 1) v += __shfl_down(v, o, 64);
        if (lane == 0)
            out[0] = v * (1.0f / (9.0f * (float)HW_));
    }
}

extern "C" void kernel_launch(void* const* d_in, const int* in_sizes, int n_in,
                              void* d_out, int out_size, void* d_ws, size_t ws_size,
                              hipStream_t stream) {
    const float* offset = (const float*)d_in[0];   // [4,18,512,512]
    const float* flow   = (const float*)d_in[1];   // [4,8,512,512]
    float* partial = (float*)d_ws;                 // GRID1 floats (4 KB), fully rewritten
    float* out     = (float*)d_out;                // 1 float

    pos_loss_main<<<GRID1, BLK, 0, stream>>>(offset, flow, partial);
    pos_loss_reduce<<<1, RBLK, 0, stream>>>(partial, out);
}